// Round 7
// baseline (1369.677 us; speedup 1.0000x reference)
//
#include <hip/hip_runtime.h>

#define N_NODES 100000
#define N_FEATS 256
#define OUT_DIM 64
#define NNZ_X   1280000
#define N_EDGES 1600000
#define NB      391     // ceil(N_NODES/256); bucket = row >> 8
#define CHUNK   4096    // entries per phase-1 block
#define CAPX    4352    // X bucket slab capacity (mean 3277, std 57: +18 sigma)
#define CAPA    5120    // A bucket slab capacity (mean 4092, std 64: +16 sigma)

// ---------------- JAX threefry2x32 (partitionable mode, verified R2) ----------------
__device__ __forceinline__ unsigned rotl32(unsigned x, unsigned d) {
    return (x << d) | (x >> (32u - d));
}

__device__ __forceinline__ float jax_uniform_42(unsigned e) {
    unsigned x0 = 0u, x1 = e;
    const unsigned ks0 = 0u, ks1 = 42u, ks2 = 0u ^ 42u ^ 0x1BD11BDAu;
    x0 += ks0; x1 += ks1;
#define TF_R(r) { x0 += x1; x1 = rotl32(x1, r); x1 ^= x0; }
    TF_R(13) TF_R(15) TF_R(26) TF_R(6)
    x0 += ks1; x1 += ks2 + 1u;
    TF_R(17) TF_R(29) TF_R(16) TF_R(24)
    x0 += ks2; x1 += ks0 + 2u;
    TF_R(13) TF_R(15) TF_R(26) TF_R(6)
    x0 += ks0; x1 += ks1 + 3u;
    TF_R(17) TF_R(29) TF_R(16) TF_R(24)
    x0 += ks1; x1 += ks2 + 4u;
    TF_R(13) TF_R(15) TF_R(26) TF_R(6)
    x0 += ks2; x1 += ks0 + 5u;
#undef TF_R
    unsigned bits = x0 ^ x1;
    return __uint_as_float((bits >> 9) | 0x3f800000u) - 1.0f;
}

// ---------------- phase 1: LDS-binned bucket grouping into fixed slabs --------
// Entry format: float2(val, int(col<<8 | row&255)). Slab b occupies
// [b*CAP, b*CAP+count_b); counts end up in bcur[b]. Dropout fused for X.
__global__ void phase1(const float* __restrict__ fvals, const int* __restrict__ frows,
                       const int* __restrict__ fcols,
                       const float* __restrict__ avals, const int* __restrict__ arows,
                       const int* __restrict__ acols,
                       int* __restrict__ bcur_x, int* __restrict__ bcur_a,
                       float2* __restrict__ gx, float2* __restrict__ ga) {
    const int isA = blockIdx.y;
    const float* vals = isA ? avals : fvals;
    const int* rows   = isA ? arows : frows;
    const int* cols   = isA ? acols : fcols;
    int* bcur         = isA ? bcur_a : bcur_x;
    float2* dst       = isA ? ga : gx;
    const unsigned cap = isA ? CAPA : CAPX;
    const unsigned n  = isA ? N_EDGES : NNZ_X;

    unsigned t = threadIdx.x;
    unsigned base = blockIdx.x * CHUNK;
    if (base >= n) return;   // uniform per block

    __shared__ int cnt[512];
    __shared__ int start[512];
    __shared__ int cur[512];
    __shared__ int gbase[NB];
    __shared__ int s[256];
    __shared__ unsigned pArr[CHUNK];   // (b<<20)|(rowlow<<12)|ilocal

    cnt[2*t] = 0; cnt[2*t+1] = 0;
    __syncthreads();
    // pass 1: count buckets
    for (int k = 0; k < CHUNK / 256; k++) {
        unsigned i = base + k * 256u + t;
        if (i < n) atomicAdd(&cnt[(unsigned)rows[i] >> 8], 1);
    }
    __syncthreads();
    // exclusive scan of cnt
    s[t] = cnt[2*t] + cnt[2*t+1];
    __syncthreads();
    for (int off = 1; off < 256; off <<= 1) {
        int v = (t >= (unsigned)off) ? s[t - off] : 0;
        __syncthreads();
        s[t] += v;
        __syncthreads();
    }
    int excl = t ? s[t-1] : 0;
    int n_valid = s[255];
    start[2*t]   = excl;
    start[2*t+1] = excl + cnt[2*t];
    cur[2*t]     = excl;
    cur[2*t+1]   = excl + cnt[2*t];
    for (unsigned b = t; b < NB; b += 256u) {
        int cb = cnt[b];
        if (cb > 0) gbase[b] = atomicAdd(&bcur[b], cb);
    }
    __syncthreads();
    // pass 2: bucket-grouped permutation (meta only)
    for (int k = 0; k < CHUNK / 256; k++) {
        unsigned i = base + k * 256u + t;
        if (i < n) {
            unsigned row = (unsigned)rows[i];
            unsigned b = row >> 8;
            int p = atomicAdd(&cur[b], 1);
            pArr[p] = (b << 20) | ((row & 255u) << 12) | (i - base);
        }
    }
    __syncthreads();
    // pass 3: coalesced writes into slabs; re-read col/val, recompute dropout
    for (int k = 0; k < CHUNK / 256; k++) {
        int sidx = k * 256 + (int)t;
        if (sidx < n_valid) {
            unsigned m = pArr[sidx];
            unsigned b = m >> 20;
            unsigned rowlow = (m >> 12) & 255u;
            unsigned i = base + (m & 4095u);
            float v = vals[i];
            if (!isA) {
                float u = jax_uniform_42(i);
                v = (floorf(0.9f + u) != 0.0f) ? v * (float)(1.0 / 0.9) : 0.0f;
            }
            unsigned packed = ((unsigned)cols[i] << 8) | rowlow;
            float2 e; e.x = v; e.y = __int_as_float((int)packed);
            dst[(size_t)b * cap + gbase[b] + (sidx - start[b])] = e;
        }
    }
}

// ---------------- SpMM1: one block per bucket, LDS f32 accumulator tile -------
// acc[256][64]; wave processes 4 entries: w = W[col][lane]; ds_add acc[rowlow][lane].
__global__ __launch_bounds__(512) void spmm1_bucket(
        const int* __restrict__ bcur, const float2* __restrict__ gx,
        const float* __restrict__ W, unsigned short* __restrict__ xw) {
    __shared__ float acc[256 * OUT_DIM];
    unsigned b = blockIdx.x;
    int cnt = bcur[b];
    const float2* ent = gx + (size_t)b * CAPX;
    unsigned t = threadIdx.x, wid = t >> 6, lane = t & 63u;
    for (int i = (int)t; i < 256 * OUT_DIM; i += 512) acc[i] = 0.0f;
    __syncthreads();
    for (int e = (int)wid * 4; e < cnt; e += 32) {
        int rem = cnt - e;
        if (rem >= 4) {
            float2 e0 = ent[e], e1 = ent[e+1], e2 = ent[e+2], e3 = ent[e+3];
            unsigned p0 = (unsigned)__float_as_int(e0.y);
            unsigned p1 = (unsigned)__float_as_int(e1.y);
            unsigned p2 = (unsigned)__float_as_int(e2.y);
            unsigned p3 = (unsigned)__float_as_int(e3.y);
            float w0 = W[(p0 >> 8) * OUT_DIM + lane];
            float w1 = W[(p1 >> 8) * OUT_DIM + lane];
            float w2 = W[(p2 >> 8) * OUT_DIM + lane];
            float w3 = W[(p3 >> 8) * OUT_DIM + lane];
            unsafeAtomicAdd(&acc[(p0 & 255u) * OUT_DIM + lane], e0.x * w0);
            unsafeAtomicAdd(&acc[(p1 & 255u) * OUT_DIM + lane], e1.x * w1);
            unsafeAtomicAdd(&acc[(p2 & 255u) * OUT_DIM + lane], e2.x * w2);
            unsafeAtomicAdd(&acc[(p3 & 255u) * OUT_DIM + lane], e3.x * w3);
        } else {
            for (int j = 0; j < rem; j++) {
                float2 e0 = ent[e + j];
                unsigned p0 = (unsigned)__float_as_int(e0.y);
                float w0 = W[(p0 >> 8) * OUT_DIM + lane];
                unsafeAtomicAdd(&acc[(p0 & 255u) * OUT_DIM + lane], e0.x * w0);
            }
        }
    }
    __syncthreads();
    // write 256 rows as bf16 (round-to-nearest-even), coalesced per wave
    for (unsigned r = wid; r < 256u; r += 8u) {
        unsigned grow = (b << 8) + r;
        if (grow < N_NODES) {
            float a = acc[r * OUT_DIM + lane];
            unsigned bits = __float_as_uint(a);
            unsigned rounded = (bits + 0x7fffu + ((bits >> 16) & 1u)) >> 16;
            xw[grow * OUT_DIM + lane] = (unsigned short)rounded;
        }
    }
}

// ---------------- SpMM2 + ReLU: one block per bucket, bf16 xw gather ----------
__global__ __launch_bounds__(512) void spmm2_bucket(
        const int* __restrict__ bcur, const float2* __restrict__ ga,
        const unsigned short* __restrict__ xw, float* __restrict__ out) {
    __shared__ float acc[256 * OUT_DIM];
    unsigned b = blockIdx.x;
    int cnt = bcur[b];
    const float2* ent = ga + (size_t)b * CAPA;
    unsigned t = threadIdx.x, wid = t >> 6, lane = t & 63u;
    for (int i = (int)t; i < 256 * OUT_DIM; i += 512) acc[i] = 0.0f;
    __syncthreads();
    for (int e = (int)wid * 4; e < cnt; e += 32) {
        int rem = cnt - e;
        if (rem >= 4) {
            float2 e0 = ent[e], e1 = ent[e+1], e2 = ent[e+2], e3 = ent[e+3];
            unsigned p0 = (unsigned)__float_as_int(e0.y);
            unsigned p1 = (unsigned)__float_as_int(e1.y);
            unsigned p2 = (unsigned)__float_as_int(e2.y);
            unsigned p3 = (unsigned)__float_as_int(e3.y);
            float x0 = __uint_as_float((unsigned)xw[(p0 >> 8) * OUT_DIM + lane] << 16);
            float x1 = __uint_as_float((unsigned)xw[(p1 >> 8) * OUT_DIM + lane] << 16);
            float x2 = __uint_as_float((unsigned)xw[(p2 >> 8) * OUT_DIM + lane] << 16);
            float x3 = __uint_as_float((unsigned)xw[(p3 >> 8) * OUT_DIM + lane] << 16);
            unsafeAtomicAdd(&acc[(p0 & 255u) * OUT_DIM + lane], e0.x * x0);
            unsafeAtomicAdd(&acc[(p1 & 255u) * OUT_DIM + lane], e1.x * x1);
            unsafeAtomicAdd(&acc[(p2 & 255u) * OUT_DIM + lane], e2.x * x2);
            unsafeAtomicAdd(&acc[(p3 & 255u) * OUT_DIM + lane], e3.x * x3);
        } else {
            for (int j = 0; j < rem; j++) {
                float2 e0 = ent[e + j];
                unsigned p0 = (unsigned)__float_as_int(e0.y);
                float x0 = __uint_as_float((unsigned)xw[(p0 >> 8) * OUT_DIM + lane] << 16);
                unsafeAtomicAdd(&acc[(p0 & 255u) * OUT_DIM + lane], e0.x * x0);
            }
        }
    }
    __syncthreads();
    for (unsigned r = wid; r < 256u; r += 8u) {
        unsigned grow = (b << 8) + r;
        if (grow < N_NODES)
            out[grow * OUT_DIM + lane] = fmaxf(acc[r * OUT_DIM + lane], 0.0f);
    }
}

extern "C" void kernel_launch(void* const* d_in, const int* in_sizes, int n_in,
                              void* d_out, int out_size, void* d_ws, size_t ws_size,
                              hipStream_t stream) {
    const float* feat_values = (const float*)d_in[0];
    const float* W           = (const float*)d_in[1];
    const float* adj_values  = (const float*)d_in[2];
    const int*   feat_rows   = (const int*)d_in[3];
    const int*   feat_cols   = (const int*)d_in[4];
    const int*   adj_rows    = (const int*)d_in[5];
    const int*   adj_cols    = (const int*)d_in[6];
    float* out = (float*)d_out;

    // ---- workspace layout (bytes) ----
    // bcur_x @ 0       (391 ints)
    // bcur_a @ 2048    (391 ints)
    // gx     @ 8192          : 391*CAPX*8 = 13,613,056
    // ga     @ 13,621,248    : 391*CAPA*8 = 16,015,360
    // xw     @ 29,636,608    : 100000*64*2 = 12,800,000   (total ~42.4 MB)
    char* ws = (char*)d_ws;
    int* bcur_x = (int*)(ws + 0);
    int* bcur_a = (int*)(ws + 2048);
    float2* gx  = (float2*)(ws + 8192);
    float2* ga  = (float2*)(ws + 13621248);
    unsigned short* xw = (unsigned short*)(ws + 29636608);

    hipMemsetAsync(ws, 0, 4096, stream);    // bucket cursors

    dim3 g391(391, 2);
    phase1<<<g391, 256, 0, stream>>>(feat_values, feat_rows, feat_cols,
                                     adj_values, adj_rows, adj_cols,
                                     bcur_x, bcur_a, gx, ga);
    spmm1_bucket<<<NB, 512, 0, stream>>>(bcur_x, gx, W, xw);
    spmm2_bucket<<<NB, 512, 0, stream>>>(bcur_a, ga, xw, out);
}

// Round 8
// 254.412 us; speedup vs baseline: 5.3837x; 5.3837x over previous
//
#include <hip/hip_runtime.h>

#define N_NODES 100000
#define N_FEATS 256
#define OUT_DIM 64
#define NNZ_X   1280000
#define N_EDGES 1600000
#define NB      391     // ceil(N_NODES/256); bucket = row >> 8
#define CHUNK   4096    // entries per phase-1 block
#define CAPX    4352    // X slab capacity (kept-mean 2949, sigma ~54: +25 sigma)
#define CAPA    5120    // A slab capacity (mean 4092, sigma ~64: +16 sigma)

// ---------------- JAX threefry2x32 (partitionable mode, verified R2) ----------------
__device__ __forceinline__ unsigned rotl32(unsigned x, unsigned d) {
    return (x << d) | (x >> (32u - d));
}

__device__ __forceinline__ float jax_uniform_42(unsigned e) {
    unsigned x0 = 0u, x1 = e;
    const unsigned ks0 = 0u, ks1 = 42u, ks2 = 0u ^ 42u ^ 0x1BD11BDAu;
    x0 += ks0; x1 += ks1;
#define TF_R(r) { x0 += x1; x1 = rotl32(x1, r); x1 ^= x0; }
    TF_R(13) TF_R(15) TF_R(26) TF_R(6)
    x0 += ks1; x1 += ks2 + 1u;
    TF_R(17) TF_R(29) TF_R(16) TF_R(24)
    x0 += ks2; x1 += ks0 + 2u;
    TF_R(13) TF_R(15) TF_R(26) TF_R(6)
    x0 += ks0; x1 += ks1 + 3u;
    TF_R(17) TF_R(29) TF_R(16) TF_R(24)
    x0 += ks1; x1 += ks2 + 4u;
    TF_R(13) TF_R(15) TF_R(26) TF_R(6)
    x0 += ks2; x1 += ks0 + 5u;
#undef TF_R
    unsigned bits = x0 ^ x1;
    return __uint_as_float((bits >> 9) | 0x3f800000u) - 1.0f;
}

__device__ __forceinline__ bool keep_42(unsigned e) {
    float u = jax_uniform_42(e);
    return floorf(0.9f + u) != 0.0f;
}

// ---------------- phase 1: LDS-binned bucket grouping into fixed slabs --------
// Entry: float2(val, int(col<<8 | row&255)). Slab b = dst[b*CAP .. b*CAP+cnt_b).
// X side: dropped entries are skipped entirely (contribute nothing downstream).
__global__ void phase1(const float* __restrict__ fvals, const int* __restrict__ frows,
                       const int* __restrict__ fcols,
                       const float* __restrict__ avals, const int* __restrict__ arows,
                       const int* __restrict__ acols,
                       int* __restrict__ bcur_x, int* __restrict__ bcur_a,
                       float2* __restrict__ gx, float2* __restrict__ ga) {
    const int isA = blockIdx.y;
    const float* vals = isA ? avals : fvals;
    const int* rows   = isA ? arows : frows;
    const int* cols   = isA ? acols : fcols;
    int* bcur         = isA ? bcur_a : bcur_x;
    float2* dst       = isA ? ga : gx;
    const unsigned cap = isA ? CAPA : CAPX;
    const unsigned n  = isA ? N_EDGES : NNZ_X;

    unsigned t = threadIdx.x;
    unsigned base = blockIdx.x * CHUNK;
    if (base >= n) return;   // uniform per block

    __shared__ int cnt[512];
    __shared__ int start[512];
    __shared__ int cur[512];
    __shared__ int gbase[NB];
    __shared__ int s[256];
    __shared__ unsigned pArr[CHUNK];   // (b<<20)|(rowlow<<12)|ilocal

    cnt[2*t] = 0; cnt[2*t+1] = 0;
    __syncthreads();
    // pass 1: count kept entries per bucket
    for (int k = 0; k < CHUNK / 256; k++) {
        unsigned i = base + k * 256u + t;
        if (i < n && (isA || keep_42(i)))
            atomicAdd(&cnt[(unsigned)rows[i] >> 8], 1);
    }
    __syncthreads();
    // exclusive scan of cnt
    s[t] = cnt[2*t] + cnt[2*t+1];
    __syncthreads();
    for (int off = 1; off < 256; off <<= 1) {
        int v = (t >= (unsigned)off) ? s[t - off] : 0;
        __syncthreads();
        s[t] += v;
        __syncthreads();
    }
    int excl = t ? s[t-1] : 0;
    int n_valid = s[255];
    start[2*t]   = excl;
    start[2*t+1] = excl + cnt[2*t];
    cur[2*t]     = excl;
    cur[2*t+1]   = excl + cnt[2*t];
    for (unsigned b = t; b < NB; b += 256u) {
        int cb = cnt[b];
        if (cb > 0) gbase[b] = atomicAdd(&bcur[b], cb);
    }
    __syncthreads();
    // pass 2: bucket-grouped permutation (meta only, kept entries)
    for (int k = 0; k < CHUNK / 256; k++) {
        unsigned i = base + k * 256u + t;
        if (i < n && (isA || keep_42(i))) {
            unsigned row = (unsigned)rows[i];
            unsigned b = row >> 8;
            int p = atomicAdd(&cur[b], 1);
            pArr[p] = (b << 20) | ((row & 255u) << 12) | (i - base);
        }
    }
    __syncthreads();
    // pass 3: coalesced slab writes; all staged X entries are keepers.
    for (int k = 0; k < CHUNK / 256; k++) {
        int sidx = k * 256 + (int)t;
        if (sidx < n_valid) {
            unsigned m = pArr[sidx];
            unsigned b = m >> 20;
            unsigned rowlow = (m >> 12) & 255u;
            unsigned i = base + (m & 4095u);
            float v = vals[i];
            if (!isA) v *= (float)(1.0 / 0.9);
            unsigned packed = ((unsigned)cols[i] << 8) | rowlow;
            float2 e; e.x = v; e.y = __int_as_float((int)packed);
            dst[(size_t)b * cap + gbase[b] + (sidx - start[b])] = e;
        }
    }
}

// ---------------- phase2-X fused with SpMM1 ------------------------------------
// Sort bucket's X entries into LDS by rowlow, then 8 waves compute 32 rows each
// with register accumulators; write xw as bf16.
__global__ __launch_bounds__(512) void phase2x_spmm1(
        const int* __restrict__ bcur_x, const float2* __restrict__ gx,
        const float* __restrict__ W, unsigned short* __restrict__ xw) {
    __shared__ float2 ent[CAPX];       // 34.8 KB
    __shared__ int hist[256];
    __shared__ int starts[256];
    __shared__ int cursor[256];
    unsigned t = threadIdx.x;
    unsigned b = blockIdx.x;
    int cnt = bcur_x[b];
    const float2* src = gx + (size_t)b * CAPX;
    if (t < 256) hist[t] = 0;
    __syncthreads();
    // pass A: histogram of rowlow
    for (int i = (int)t; i < cnt; i += 512)
        atomicAdd(&hist[((unsigned)__float_as_int(src[i].y)) & 255u], 1);
    __syncthreads();
    // exclusive scan (first 256 threads)
    if (t < 256) {
        for (int off = 1; off < 256; off <<= 1) {
            int v = (t >= (unsigned)off) ? hist[t - off] : 0;
            __syncthreads();
            hist[t] += v;
            __syncthreads();
        }
        int excl = t ? hist[t - 1] : 0;
        starts[t] = excl;
        cursor[t] = excl;
    } else {
        for (int off = 1; off < 256; off <<= 1) { __syncthreads(); __syncthreads(); }
    }
    __syncthreads();
    // pass B: scatter into LDS sorted by rowlow (src re-read: L1/L2 hot)
    for (int i = (int)t; i < cnt; i += 512) {
        float2 e = src[i];
        int pos = atomicAdd(&cursor[((unsigned)__float_as_int(e.y)) & 255u], 1);
        ent[pos] = e;
    }
    __syncthreads();
    // compute: wave wid owns rows wid, wid+8, ...
    unsigned wid = t >> 6, lane = t & 63u;
    for (unsigned r = wid; r < 256u; r += 8u) {
        int s0 = starts[r];
        int s1 = (r == 255u) ? cnt : starts[r + 1];
        float acc0 = 0.0f, acc1 = 0.0f, acc2 = 0.0f, acc3 = 0.0f;
        int p = s0;
        for (; p + 4 <= s1; p += 4) {
            float2 e0 = ent[p], e1 = ent[p+1], e2 = ent[p+2], e3 = ent[p+3];
            float w0 = W[(((unsigned)__float_as_int(e0.y)) >> 8) * OUT_DIM + lane];
            float w1 = W[(((unsigned)__float_as_int(e1.y)) >> 8) * OUT_DIM + lane];
            float w2 = W[(((unsigned)__float_as_int(e2.y)) >> 8) * OUT_DIM + lane];
            float w3 = W[(((unsigned)__float_as_int(e3.y)) >> 8) * OUT_DIM + lane];
            acc0 = fmaf(e0.x, w0, acc0);
            acc1 = fmaf(e1.x, w1, acc1);
            acc2 = fmaf(e2.x, w2, acc2);
            acc3 = fmaf(e3.x, w3, acc3);
        }
        for (; p < s1; p++) {
            float2 e = ent[p];
            acc0 = fmaf(e.x, W[(((unsigned)__float_as_int(e.y)) >> 8) * OUT_DIM + lane], acc0);
        }
        unsigned grow = (b << 8) + r;
        if (grow < N_NODES) {
            float a = (acc0 + acc1) + (acc2 + acc3);
            unsigned bits = __float_as_uint(a);
            unsigned rounded = (bits + 0x7fffu + ((bits >> 16) & 1u)) >> 16;
            xw[(size_t)grow * OUT_DIM + lane] = (unsigned short)rounded;
        }
    }
}

// ---------------- phase2-A: per-bucket row sort (slab in place) + local starts -
__global__ __launch_bounds__(512) void phase2a(
        const int* __restrict__ bcur_a, float2* __restrict__ ga,
        unsigned short* __restrict__ rs) {
    __shared__ float2 ent[CAPA];       // 41 KB
    __shared__ int hist[256];
    __shared__ int starts[256];
    __shared__ int cursor[256];
    unsigned t = threadIdx.x;
    unsigned b = blockIdx.x;
    int cnt = bcur_a[b];
    float2* g = ga + (size_t)b * CAPA;
    if (t < 256) hist[t] = 0;
    __syncthreads();
    for (int i = (int)t; i < cnt; i += 512) {
        float2 e = g[i];
        ent[i] = e;
        atomicAdd(&hist[((unsigned)__float_as_int(e.y)) & 255u], 1);
    }
    __syncthreads();
    if (t < 256) {
        for (int off = 1; off < 256; off <<= 1) {
            int v = (t >= (unsigned)off) ? hist[t - off] : 0;
            __syncthreads();
            hist[t] += v;
            __syncthreads();
        }
        int excl = t ? hist[t - 1] : 0;
        starts[t] = excl;
        cursor[t] = excl;
        rs[(b << 8) + t] = (unsigned short)excl;   // local row start
    } else {
        for (int off = 1; off < 256; off <<= 1) { __syncthreads(); __syncthreads(); }
    }
    __syncthreads();
    // scatter back to slab sorted by rowlow; store (val, col)
    for (int i = (int)t; i < cnt; i += 512) {
        float2 e = ent[i];
        unsigned packed = (unsigned)__float_as_int(e.y);
        int pos = atomicAdd(&cursor[packed & 255u], 1);
        float2 o; o.x = e.x; o.y = __int_as_float((int)(packed >> 8));
        g[pos] = o;
    }
}

// ---------------- SpMM2 + ReLU: wave per row, unroll 8, bf16 xw gather ---------
__global__ void spmm2_csr(const int* __restrict__ bcur_a,
                          const unsigned short* __restrict__ rs,
                          const float2* __restrict__ ga,
                          const unsigned short* __restrict__ xw,
                          float* __restrict__ out) {
    unsigned row  = blockIdx.x * 4u + (threadIdx.x >> 6);
    unsigned lane = threadIdx.x & 63u;
    if (row >= N_NODES) return;
    unsigned b = row >> 8, rl = row & 255u;
    int cnt = bcur_a[b];
    const float2* ent = ga + (size_t)b * CAPA;
    int s0 = rs[row];
    int s1 = (rl == 255u) ? cnt : (int)rs[row + 1];
    float a0 = 0.f, a1 = 0.f, a2 = 0.f, a3 = 0.f, a4 = 0.f, a5 = 0.f, a6 = 0.f, a7 = 0.f;
    int p = s0;
    for (; p + 8 <= s1; p += 8) {
        float2 e0 = ent[p],   e1 = ent[p+1], e2 = ent[p+2], e3 = ent[p+3];
        float2 e4 = ent[p+4], e5 = ent[p+5], e6 = ent[p+6], e7 = ent[p+7];
        float x0 = __uint_as_float((unsigned)xw[((unsigned)__float_as_int(e0.y)) * OUT_DIM + lane] << 16);
        float x1 = __uint_as_float((unsigned)xw[((unsigned)__float_as_int(e1.y)) * OUT_DIM + lane] << 16);
        float x2 = __uint_as_float((unsigned)xw[((unsigned)__float_as_int(e2.y)) * OUT_DIM + lane] << 16);
        float x3 = __uint_as_float((unsigned)xw[((unsigned)__float_as_int(e3.y)) * OUT_DIM + lane] << 16);
        float x4 = __uint_as_float((unsigned)xw[((unsigned)__float_as_int(e4.y)) * OUT_DIM + lane] << 16);
        float x5 = __uint_as_float((unsigned)xw[((unsigned)__float_as_int(e5.y)) * OUT_DIM + lane] << 16);
        float x6 = __uint_as_float((unsigned)xw[((unsigned)__float_as_int(e6.y)) * OUT_DIM + lane] << 16);
        float x7 = __uint_as_float((unsigned)xw[((unsigned)__float_as_int(e7.y)) * OUT_DIM + lane] << 16);
        a0 = fmaf(e0.x, x0, a0); a1 = fmaf(e1.x, x1, a1);
        a2 = fmaf(e2.x, x2, a2); a3 = fmaf(e3.x, x3, a3);
        a4 = fmaf(e4.x, x4, a4); a5 = fmaf(e5.x, x5, a5);
        a6 = fmaf(e6.x, x6, a6); a7 = fmaf(e7.x, x7, a7);
    }
    for (; p < s1; p++) {
        float2 e = ent[p];
        float x = __uint_as_float((unsigned)xw[((unsigned)__float_as_int(e.y)) * OUT_DIM + lane] << 16);
        a0 = fmaf(e.x, x, a0);
    }
    float acc = ((a0 + a1) + (a2 + a3)) + ((a4 + a5) + (a6 + a7));
    out[(size_t)row * OUT_DIM + lane] = fmaxf(acc, 0.0f);
}

extern "C" void kernel_launch(void* const* d_in, const int* in_sizes, int n_in,
                              void* d_out, int out_size, void* d_ws, size_t ws_size,
                              hipStream_t stream) {
    const float* feat_values = (const float*)d_in[0];
    const float* W           = (const float*)d_in[1];
    const float* adj_values  = (const float*)d_in[2];
    const int*   feat_rows   = (const int*)d_in[3];
    const int*   feat_cols   = (const int*)d_in[4];
    const int*   adj_rows    = (const int*)d_in[5];
    const int*   adj_cols    = (const int*)d_in[6];
    float* out = (float*)d_out;

    // ---- workspace layout (bytes) ----
    // bcur_x @ 0 (391 ints), bcur_a @ 2048
    // rs_a   @ 4096        : 100096 ushort = 200,192
    // gx     @ 204800      : 391*CAPX*8 = 13,613,056
    // ga     @ 13,817,856  : 391*CAPA*8 = 16,015,360
    // xw     @ 29,833,216  : 100000*64*2 = 12,800,000   (total ~42.6 MB)
    char* ws = (char*)d_ws;
    int* bcur_x = (int*)(ws + 0);
    int* bcur_a = (int*)(ws + 2048);
    unsigned short* rs_a = (unsigned short*)(ws + 4096);
    float2* gx  = (float2*)(ws + 204800);
    float2* ga  = (float2*)(ws + 13817856);
    unsigned short* xw = (unsigned short*)(ws + 29833216);

    hipMemsetAsync(ws, 0, 4096, stream);    // bucket cursors

    dim3 g391(391, 2);
    phase1<<<g391, 256, 0, stream>>>(feat_values, feat_rows, feat_cols,
                                     adj_values, adj_rows, adj_cols,
                                     bcur_x, bcur_a, gx, ga);
    phase2x_spmm1<<<NB, 512, 0, stream>>>(bcur_x, gx, W, xw);
    phase2a<<<NB, 512, 0, stream>>>(bcur_a, ga, rs_a);
    spmm2_csr<<<(N_NODES + 3) / 4, 256, 0, stream>>>(bcur_a, rs_a, ga, xw, out);
}

// Round 9
// 231.352 us; speedup vs baseline: 5.9203x; 1.0997x over previous
//
#include <hip/hip_runtime.h>

#define N_NODES 100000
#define N_FEATS 256
#define OUT_DIM 64
#define NNZ_X   1280000
#define N_EDGES 1600000
#define NB      391     // ceil(N_NODES/256); bucket = row >> 8
#define CHUNK   2048    // entries per phase-1 block
#define KPT     8       // CHUNK/256 entries per thread
#define CAPX    4352    // X slab capacity (kept-mean 2949, sigma ~54: +25 sigma)
#define CAPA    5120    // A slab capacity (mean 4092, sigma ~64: +16 sigma)

// ---------------- JAX threefry2x32 (partitionable mode, verified R2) ----------------
__device__ __forceinline__ unsigned rotl32(unsigned x, unsigned d) {
    return (x << d) | (x >> (32u - d));
}

__device__ __forceinline__ float jax_uniform_42(unsigned e) {
    unsigned x0 = 0u, x1 = e;
    const unsigned ks0 = 0u, ks1 = 42u, ks2 = 0u ^ 42u ^ 0x1BD11BDAu;
    x0 += ks0; x1 += ks1;
#define TF_R(r) { x0 += x1; x1 = rotl32(x1, r); x1 ^= x0; }
    TF_R(13) TF_R(15) TF_R(26) TF_R(6)
    x0 += ks1; x1 += ks2 + 1u;
    TF_R(17) TF_R(29) TF_R(16) TF_R(24)
    x0 += ks2; x1 += ks0 + 2u;
    TF_R(13) TF_R(15) TF_R(26) TF_R(6)
    x0 += ks0; x1 += ks1 + 3u;
    TF_R(17) TF_R(29) TF_R(16) TF_R(24)
    x0 += ks1; x1 += ks2 + 4u;
    TF_R(13) TF_R(15) TF_R(26) TF_R(6)
    x0 += ks2; x1 += ks0 + 5u;
#undef TF_R
    unsigned bits = x0 ^ x1;
    return __uint_as_float((bits >> 9) | 0x3f800000u) - 1.0f;
}

__device__ __forceinline__ bool keep_42(unsigned e) {
    float u = jax_uniform_42(e);
    return floorf(0.9f + u) != 0.0f;
}

// ---------------- phase 1: LDS-binned bucket grouping into fixed slabs --------
// Entry: float2(val, int(col<<8 | row&255)). Slab b = dst[b*CAP .. b*CAP+cnt_b).
// rows read ONCE (cached in VGPRs with keep flag); dropped X entries skipped.
__global__ void phase1(const float* __restrict__ fvals, const int* __restrict__ frows,
                       const int* __restrict__ fcols,
                       const float* __restrict__ avals, const int* __restrict__ arows,
                       const int* __restrict__ acols,
                       int* __restrict__ bcur_x, int* __restrict__ bcur_a,
                       float2* __restrict__ gx, float2* __restrict__ ga) {
    const int isA = blockIdx.y;
    const float* vals = isA ? avals : fvals;
    const int* rows   = isA ? arows : frows;
    const int* cols   = isA ? acols : fcols;
    int* bcur         = isA ? bcur_a : bcur_x;
    float2* dst       = isA ? ga : gx;
    const unsigned cap = isA ? CAPA : CAPX;
    const unsigned n  = isA ? N_EDGES : NNZ_X;

    unsigned t = threadIdx.x;
    unsigned base = blockIdx.x * CHUNK;
    if (base >= n) return;   // uniform per block (X side has fewer chunks)

    __shared__ int cnt[512];
    __shared__ int start[512];
    __shared__ int cur[512];
    __shared__ int gbase[NB];
    __shared__ int s[256];
    __shared__ unsigned pArr[CHUNK];   // (b<<19)|(rowlow<<11)|ilocal

    int rcache[KPT];                   // row if kept, else -1

    cnt[2*t] = 0; cnt[2*t+1] = 0;
    __syncthreads();
    // pass 1: read rows once, hist kept entries per bucket
    #pragma unroll
    for (int k = 0; k < KPT; k++) {
        unsigned i = base + k * 256u + t;
        int r = -1;
        if (i < n) {
            int rr = rows[i];
            if (isA || keep_42(i)) r = rr;
        }
        rcache[k] = r;
        if (r >= 0) atomicAdd(&cnt[(unsigned)r >> 8], 1);
    }
    __syncthreads();
    // exclusive scan of cnt (2 bins / thread)
    s[t] = cnt[2*t] + cnt[2*t+1];
    __syncthreads();
    for (int off = 1; off < 256; off <<= 1) {
        int v = (t >= (unsigned)off) ? s[t - off] : 0;
        __syncthreads();
        s[t] += v;
        __syncthreads();
    }
    int excl = t ? s[t-1] : 0;
    int n_valid = s[255];
    start[2*t]   = excl;
    start[2*t+1] = excl + cnt[2*t];
    cur[2*t]     = excl;
    cur[2*t+1]   = excl + cnt[2*t];
    for (unsigned b = t; b < NB; b += 256u) {
        int cb = cnt[b];
        if (cb > 0) gbase[b] = atomicAdd(&bcur[b], cb);
    }
    __syncthreads();
    // pass 2: bucket-grouped permutation from the register cache (no re-read)
    #pragma unroll
    for (int k = 0; k < KPT; k++) {
        int r = rcache[k];
        if (r >= 0) {
            unsigned b = (unsigned)r >> 8;
            int p = atomicAdd(&cur[b], 1);
            pArr[p] = (b << 19) | (((unsigned)r & 255u) << 11) | (k * 256u + t);
        }
    }
    __syncthreads();
    // pass 3: coalesced slab writes; gather cols/vals from the 8KB window (L1-hot)
    #pragma unroll
    for (int k = 0; k < KPT; k++) {
        int sidx = k * 256 + (int)t;
        if (sidx < n_valid) {
            unsigned m = pArr[sidx];
            unsigned b = m >> 19;
            unsigned rowlow = (m >> 11) & 255u;
            unsigned i = base + (m & 2047u);
            float v = vals[i];
            if (!isA) v *= (float)(1.0 / 0.9);
            unsigned packed = ((unsigned)cols[i] << 8) | rowlow;
            float2 e; e.x = v; e.y = __int_as_float((int)packed);
            dst[(size_t)b * cap + gbase[b] + (sidx - start[b])] = e;
        }
    }
}

// ---------------- fused sort stage: grid 2*NB ----------------------------------
// blocks [0, NB)      : X bucket -> LDS row-sort -> SpMM1 -> bf16 xw
// blocks [NB, 2*NB)   : A bucket -> LDS row-sort -> write back slab + rs_a
__global__ __launch_bounds__(512) void sort_stage(
        const int* __restrict__ bcur_x, const float2* __restrict__ gx,
        const float* __restrict__ W, unsigned short* __restrict__ xw,
        const int* __restrict__ bcur_a, float2* __restrict__ ga,
        unsigned short* __restrict__ rs) {
    __shared__ float2 ent[CAPA];       // 41 KB (CAPA >= CAPX)
    __shared__ int hist[256];
    __shared__ int starts[256];
    __shared__ int cursor[256];
    unsigned t = threadIdx.x;
    const int isA = (blockIdx.x >= NB);
    unsigned b = isA ? (blockIdx.x - NB) : blockIdx.x;

    if (!isA) {
        // ---------------- X path: sort into LDS, compute SpMM1 ----------------
        int cnt = bcur_x[b];
        const float2* src = gx + (size_t)b * CAPX;
        if (t < 256) hist[t] = 0;
        __syncthreads();
        for (int i = (int)t; i < cnt; i += 512)
            atomicAdd(&hist[((unsigned)__float_as_int(src[i].y)) & 255u], 1);
        __syncthreads();
        if (t < 256) {
            for (int off = 1; off < 256; off <<= 1) {
                int v = (t >= (unsigned)off) ? hist[t - off] : 0;
                __syncthreads();
                hist[t] += v;
                __syncthreads();
            }
            int excl = t ? hist[t - 1] : 0;
            starts[t] = excl;
            cursor[t] = excl;
        } else {
            for (int off = 1; off < 256; off <<= 1) { __syncthreads(); __syncthreads(); }
        }
        __syncthreads();
        for (int i = (int)t; i < cnt; i += 512) {
            float2 e = src[i];
            int pos = atomicAdd(&cursor[((unsigned)__float_as_int(e.y)) & 255u], 1);
            ent[pos] = e;
        }
        __syncthreads();
        unsigned wid = t >> 6, lane = t & 63u;
        for (unsigned r = wid; r < 256u; r += 8u) {
            int s0 = starts[r];
            int s1 = (r == 255u) ? cnt : starts[r + 1];
            float acc0 = 0.0f, acc1 = 0.0f, acc2 = 0.0f, acc3 = 0.0f;
            int p = s0;
            for (; p + 4 <= s1; p += 4) {
                float2 e0 = ent[p], e1 = ent[p+1], e2 = ent[p+2], e3 = ent[p+3];
                float w0 = W[(((unsigned)__float_as_int(e0.y)) >> 8) * OUT_DIM + lane];
                float w1 = W[(((unsigned)__float_as_int(e1.y)) >> 8) * OUT_DIM + lane];
                float w2 = W[(((unsigned)__float_as_int(e2.y)) >> 8) * OUT_DIM + lane];
                float w3 = W[(((unsigned)__float_as_int(e3.y)) >> 8) * OUT_DIM + lane];
                acc0 = fmaf(e0.x, w0, acc0);
                acc1 = fmaf(e1.x, w1, acc1);
                acc2 = fmaf(e2.x, w2, acc2);
                acc3 = fmaf(e3.x, w3, acc3);
            }
            for (; p < s1; p++) {
                float2 e = ent[p];
                acc0 = fmaf(e.x, W[(((unsigned)__float_as_int(e.y)) >> 8) * OUT_DIM + lane], acc0);
            }
            unsigned grow = (b << 8) + r;
            if (grow < N_NODES) {
                float a = (acc0 + acc1) + (acc2 + acc3);
                unsigned bits = __float_as_uint(a);
                unsigned rounded = (bits + 0x7fffu + ((bits >> 16) & 1u)) >> 16;
                xw[(size_t)grow * OUT_DIM + lane] = (unsigned short)rounded;
            }
        }
    } else {
        // ---------------- A path: sort slab in place + local row starts -------
        int cnt = bcur_a[b];
        float2* g = ga + (size_t)b * CAPA;
        if (t < 256) hist[t] = 0;
        __syncthreads();
        for (int i = (int)t; i < cnt; i += 512) {
            float2 e = g[i];
            ent[i] = e;
            atomicAdd(&hist[((unsigned)__float_as_int(e.y)) & 255u], 1);
        }
        __syncthreads();
        if (t < 256) {
            for (int off = 1; off < 256; off <<= 1) {
                int v = (t >= (unsigned)off) ? hist[t - off] : 0;
                __syncthreads();
                hist[t] += v;
                __syncthreads();
            }
            int excl = t ? hist[t - 1] : 0;
            cursor[t] = excl;
            rs[(b << 8) + t] = (unsigned short)excl;
        } else {
            for (int off = 1; off < 256; off <<= 1) { __syncthreads(); __syncthreads(); }
        }
        __syncthreads();
        for (int i = (int)t; i < cnt; i += 512) {
            float2 e = ent[i];
            unsigned packed = (unsigned)__float_as_int(e.y);
            int pos = atomicAdd(&cursor[packed & 255u], 1);
            float2 o; o.x = e.x; o.y = __int_as_float((int)(packed >> 8));
            g[pos] = o;
        }
    }
}

// ---------------- SpMM2 + ReLU: wave per row, unroll 16, bf16 xw gather --------
__global__ void spmm2_csr(const int* __restrict__ bcur_a,
                          const unsigned short* __restrict__ rs,
                          const float2* __restrict__ ga,
                          const unsigned short* __restrict__ xw,
                          float* __restrict__ out) {
    unsigned row  = blockIdx.x * 4u + (threadIdx.x >> 6);
    unsigned lane = threadIdx.x & 63u;
    if (row >= N_NODES) return;
    unsigned b = row >> 8, rl = row & 255u;
    int cnt = bcur_a[b];
    const float2* ent = ga + (size_t)b * CAPA;
    int s0 = rs[row];
    int s1 = (rl == 255u) ? cnt : (int)rs[row + 1];
    float a[8];
    #pragma unroll
    for (int j = 0; j < 8; j++) a[j] = 0.0f;
    int p = s0;
    // 16-entry batches: all ent loads issued, then all gathers — one chain per batch
    for (; p + 16 <= s1; p += 16) {
        float2 e[16];
        #pragma unroll
        for (int j = 0; j < 16; j++) e[j] = ent[p + j];
        float x[16];
        #pragma unroll
        for (int j = 0; j < 16; j++)
            x[j] = __uint_as_float((unsigned)xw[((unsigned)__float_as_int(e[j].y)) * OUT_DIM + lane] << 16);
        #pragma unroll
        for (int j = 0; j < 16; j++)
            a[j & 7] = fmaf(e[j].x, x[j], a[j & 7]);
    }
    for (; p + 4 <= s1; p += 4) {
        float2 e[4];
        #pragma unroll
        for (int j = 0; j < 4; j++) e[j] = ent[p + j];
        #pragma unroll
        for (int j = 0; j < 4; j++) {
            float x = __uint_as_float((unsigned)xw[((unsigned)__float_as_int(e[j].y)) * OUT_DIM + lane] << 16);
            a[j] = fmaf(e[j].x, x, a[j]);
        }
    }
    for (; p < s1; p++) {
        float2 e = ent[p];
        float x = __uint_as_float((unsigned)xw[((unsigned)__float_as_int(e.y)) * OUT_DIM + lane] << 16);
        a[0] = fmaf(e.x, x, a[0]);
    }
    float acc = ((a[0] + a[1]) + (a[2] + a[3])) + ((a[4] + a[5]) + (a[6] + a[7]));
    out[(size_t)row * OUT_DIM + lane] = fmaxf(acc, 0.0f);
}

extern "C" void kernel_launch(void* const* d_in, const int* in_sizes, int n_in,
                              void* d_out, int out_size, void* d_ws, size_t ws_size,
                              hipStream_t stream) {
    const float* feat_values = (const float*)d_in[0];
    const float* W           = (const float*)d_in[1];
    const float* adj_values  = (const float*)d_in[2];
    const int*   feat_rows   = (const int*)d_in[3];
    const int*   feat_cols   = (const int*)d_in[4];
    const int*   adj_rows    = (const int*)d_in[5];
    const int*   adj_cols    = (const int*)d_in[6];
    float* out = (float*)d_out;

    // ---- workspace layout (bytes) ----
    // bcur_x @ 0 (391 ints), bcur_a @ 2048
    // rs_a   @ 4096        : 100096 ushort = 200,192
    // gx     @ 204800      : 391*CAPX*8 = 13,613,056
    // ga     @ 13,817,856  : 391*CAPA*8 = 16,015,360
    // xw     @ 29,833,216  : 100000*64*2 = 12,800,000   (total ~42.6 MB)
    char* ws = (char*)d_ws;
    int* bcur_x = (int*)(ws + 0);
    int* bcur_a = (int*)(ws + 2048);
    unsigned short* rs_a = (unsigned short*)(ws + 4096);
    float2* gx  = (float2*)(ws + 204800);
    float2* ga  = (float2*)(ws + 13817856);
    unsigned short* xw = (unsigned short*)(ws + 29833216);

    hipMemsetAsync(ws, 0, 4096, stream);    // bucket cursors

    // phase1: grid sized for the larger (A) side; X blocks past 625 early-exit
    dim3 gp1((N_EDGES + CHUNK - 1) / CHUNK, 2);
    phase1<<<gp1, 256, 0, stream>>>(feat_values, feat_rows, feat_cols,
                                    adj_values, adj_rows, adj_cols,
                                    bcur_x, bcur_a, gx, ga);
    sort_stage<<<2 * NB, 512, 0, stream>>>(bcur_x, gx, W, xw, bcur_a, ga, rs_a);
    spmm2_csr<<<(N_NODES + 3) / 4, 256, 0, stream>>>(bcur_a, rs_a, ga, xw, out);
}